// Round 5
// baseline (1454.729 us; speedup 1.0000x reference)
//
#include <hip/hip_runtime.h>
#include <hip/hip_bf16.h>
#include <hip/hip_fp16.h>
#include <type_traits>

#define B_  8
#define LO_ 512
#define E_  768
#define H_  12
#define S_  2048

typedef __attribute__((ext_vector_type(8))) short bf16x8;
typedef __attribute__((ext_vector_type(4))) float f32x4;
#define MFMA16(a,b,c) __builtin_amdgcn_mfma_f32_16x16x32_bf16(a, b, c, 0, 0, 0)

__device__ inline short f2bf(float f) {
  __hip_bfloat16 h = __float2bfloat16(f);
  return *reinterpret_cast<short*>(&h);
}
__device__ inline short f2h_raw(float f) {
  __half h = __float2half(f);
  return *reinterpret_cast<short*>(&h);
}
__device__ inline float h2f_raw(short s) {
  __half h = *reinterpret_cast<__half*>(&s);
  return __half2float(h);
}

// ================= MFMA GEMM: C[r][c] = sum_k A[r][k]*W[c][k] + bias[c] ==========
// (unchanged from round 4 — correct and adequate; optimize next round if it tops profile)
template <typename TC>
__global__ __launch_bounds__(256) void gemm_mfma(
    const float* __restrict__ A, const float* __restrict__ W,
    const float* __restrict__ bias, TC* __restrict__ C, int R)
{
  constexpr int N = 768, K = 768;
  __shared__ short As[64*72] __attribute__((aligned(16)));
  __shared__ short Ws[64*72] __attribute__((aligned(16)));
  const int tid = threadIdx.x, wv = tid >> 6, lane = tid & 63;
  const int quad = lane >> 4, l15 = lane & 15;
  const int r0 = blockIdx.x * 64, c0 = blockIdx.y * 64;
  const int srow = tid >> 2, sk = (tid & 3) * 16;

  f32x4 acc[4] = {};

  for (int k0 = 0; k0 < K; k0 += 64) {
    float a16[16], w16[16];
    const float4* ga = (const float4*)(A + (size_t)(r0 + srow) * K + k0 + sk);
    const float4* gw = (const float4*)(W + (size_t)(c0 + srow) * K + k0 + sk);
#pragma unroll
    for (int i = 0; i < 4; ++i) {
      float4 va = ga[i]; a16[4*i] = va.x; a16[4*i+1] = va.y; a16[4*i+2] = va.z; a16[4*i+3] = va.w;
      float4 vw = gw[i]; w16[4*i] = vw.x; w16[4*i+1] = vw.y; w16[4*i+2] = vw.z; w16[4*i+3] = vw.w;
    }
    bf16x8 pa[2], pw[2];
#pragma unroll
    for (int g = 0; g < 2; ++g)
#pragma unroll
      for (int i = 0; i < 8; ++i) { pa[g][i] = f2bf(a16[g*8+i]); pw[g][i] = f2bf(w16[g*8+i]); }
    __syncthreads();
    *(bf16x8*)&As[srow*72 + sk]     = pa[0];
    *(bf16x8*)&As[srow*72 + sk + 8] = pa[1];
    *(bf16x8*)&Ws[srow*72 + sk]     = pw[0];
    *(bf16x8*)&Ws[srow*72 + sk + 8] = pw[1];
    __syncthreads();

    bf16x8 af0 = *(const bf16x8*)&As[(wv*16 + l15)*72 +      quad*8];
    bf16x8 af1 = *(const bf16x8*)&As[(wv*16 + l15)*72 + 32 + quad*8];
#pragma unroll
    for (int ct = 0; ct < 4; ++ct) {
      bf16x8 bf0 = *(const bf16x8*)&Ws[(ct*16 + l15)*72 +      quad*8];
      bf16x8 bf1 = *(const bf16x8*)&Ws[(ct*16 + l15)*72 + 32 + quad*8];
      acc[ct] = MFMA16(af0, bf0, acc[ct]);
      acc[ct] = MFMA16(af1, bf1, acc[ct]);
    }
  }

#pragma unroll
  for (int ct = 0; ct < 4; ++ct) {
    const int col = c0 + ct*16 + l15;
    const float bv = bias[col];
#pragma unroll
    for (int r = 0; r < 4; ++r) {
      const int row = r0 + wv*16 + quad*4 + r;
      const float v = acc[ct][r] + bv;
      if constexpr (std::is_same_v<TC, float>) C[(size_t)row * N + col] = v;
      else                                     C[(size_t)row * N + col] = __float2bfloat16(v);
    }
  }
}

// ================= single-pass attention =================
// grid: (b, qt16) = 8*32 = 256 blocks, 512 thr = 8 waves, dynamic LDS 153,216 B.
// Per head: S=QK*scale+mask -> LDS fp16 (full 16x2048); exact softmax; in-place
// P transform (bf16) + fused avg-RMW; PV by MFMA; plain ctx store.
#define OFF_S   0          // [16 chunks][16][136] fp16 scores -> bf16 P   (69,632 B)
#define OFF_K   69632      // [256][72] bf16 K stage                        (36,864 B)
#define OFF_V   106496     // [64][264] bf16 V^T stage                      (33,792 B)
#define OFF_Q   140288     // [2][16][72] bf16 q1/q2 tiles                   (4,608 B)
#define OFF_O   144896     // [8][256] f32 obuf                              (8,192 B)
#define OFF_M   153088     // [16] f32 row max
#define OFF_IL  153152     // [16] f32 row 1/l
#define SMEM_MAIN 153216

__global__ __launch_bounds__(512, 1) void attn_main(
    const __hip_bfloat16* __restrict__ q1, const __hip_bfloat16* __restrict__ q2,
    const __hip_bfloat16* __restrict__ k1, const __hip_bfloat16* __restrict__ v1,
    const __hip_bfloat16* __restrict__ k2, const __hip_bfloat16* __restrict__ v2,
    const float* __restrict__ mask,
    float* __restrict__ ctx, float* __restrict__ avg)
{
  extern __shared__ char smem[];
  short* Sl   = (short*)(smem + OFF_S);    // chunk stride 2176 shorts, row stride 136
  short* kbuf = (short*)(smem + OFF_K);    // row stride 72
  unsigned short* vTb = (unsigned short*)(smem + OFF_V);  // row(dim) stride 264
  short* qtl  = (short*)(smem + OFF_Q);    // src stride 1152, row stride 72
  float* obuf = (float*)(smem + OFF_O);
  float* mrow = (float*)(smem + OFF_M);
  float* ilrow= (float*)(smem + OFF_IL);

  const int tid = threadIdx.x, wv = tid >> 6, lane = tid & 63;
  const int quad = lane >> 4, l15 = lane & 15;
  const int cpr = wv >> 2, ct = wv & 3;
  const int qt = blockIdx.x & 31, b = blockIdx.x >> 5;
  const int r0 = qt * 16;

  const int srow = tid >> 1, sc = (tid & 1) * 32;   // staging: 2 thr/row, 32 shorts each

#pragma unroll 1
  for (int h = 0; h < H_; ++h) {
    __syncthreads();  // previous head's LDS reads complete
    // ---- stage q1,q2 tiles ----
    if (tid < 128) {
      const int src = tid >> 6, row = (tid >> 2) & 15, c = (tid & 3) * 16;
      const uint4* g = (const uint4*)((src ? q2 : q1) + ((size_t)(b*LO_ + r0 + row))*E_ + h*64 + c);
      *(uint4*)&qtl[src*1152 + row*72 + c]     = g[0];
      *(uint4*)&qtl[src*1152 + row*72 + c + 8] = g[1];
    }
    __syncthreads();
    bf16x8 qa[2][2];
#pragma unroll
    for (int s = 0; s < 2; ++s)
#pragma unroll
      for (int ks = 0; ks < 2; ++ks)
        qa[s][ks] = *(const bf16x8*)&qtl[s*1152 + l15*72 + ks*32 + quad*8];

    // ---- Phase A: S = QK*scale + mask -> Sl (fp16) ----
#pragma unroll 1
    for (int cp8 = 0; cp8 < 8; ++cp8) {
      const __hip_bfloat16* ksrc = (cp8 < 4) ? k1 : k2;
      const int kb0 = (cp8 & 3) * 256;
      const uint4* gk = (const uint4*)(ksrc + ((size_t)(b*1024 + kb0 + srow))*E_ + h*64 + sc);
      uint4 kr[4];
#pragma unroll
      for (int i = 0; i < 4; ++i) kr[i] = gk[i];
      __syncthreads();
#pragma unroll
      for (int i = 0; i < 4; ++i) *(uint4*)&kbuf[srow*72 + sc + i*8] = kr[i];
      __syncthreads();

      const int s = cp8 >> 2;
#pragma unroll
      for (int ksub = 0; ksub < 2; ++ksub) {
        const int nb = wv*32 + ksub*16;
        bf16x8 b0 = *(const bf16x8*)&kbuf[(nb + l15)*72 +      quad*8];
        bf16x8 b1 = *(const bf16x8*)&kbuf[(nb + l15)*72 + 32 + quad*8];
        f32x4 sacc = {};
        sacc = MFMA16(qa[s][0], b0, sacc);
        sacc = MFMA16(qa[s][1], b1, sacc);
        const int gcol = cp8*256 + nb + l15;
        const int cpi = gcol >> 7, cic = gcol & 127;
#pragma unroll
        for (int r = 0; r < 4; ++r) {
          const int row = quad*4 + r;
          const float v = sacc[r]*0.125f + mask[(size_t)(r0 + row)*S_ + gcol];
          Sl[cpi*2176 + row*136 + cic] = f2h_raw(v);
        }
      }
    }
    __syncthreads();

    // ---- exact softmax stats per row (32 threads/row, same wave) ----
    {
      const int rr = tid >> 5, j = tid & 31;
      float m = -3.0e38f, l = 0.f;
#pragma unroll
      for (int p = 0; p < 8; ++p) {
        const int gcol = j*8 + p*256;
        const int cpi = gcol >> 7, cic = gcol & 127;
        bf16x8 raw = *(const bf16x8*)&Sl[cpi*2176 + rr*136 + cic];
#pragma unroll
        for (int i = 0; i < 8; ++i) {
          const float v = h2f_raw(raw[i]);
          const float mn = fmaxf(m, v);
          l = l*__expf(m - mn) + __expf(v - mn);
          m = mn;
        }
      }
#pragma unroll
      for (int off = 1; off < 32; off <<= 1) {
        const float mo = __shfl_xor(m, off, 64);
        const float lo = __shfl_xor(l, off, 64);
        const float mn = fmaxf(m, mo);
        l = l*__expf(m - mn) + lo*__expf(mo - mn);
        m = mn;
      }
      if (j == 0) { mrow[rr] = m; ilrow[rr] = 1.0f / l; }
    }
    __syncthreads();

    // ---- P transform in place (fp16 S -> bf16 P) + fused avg RMW (/12) ----
    {
      constexpr float inv12 = 1.0f / 12.0f;
#pragma unroll 1
      for (int it = 0; it < 8; ++it) {
        const int seg = tid + it*512;
        const int cpi = seg >> 8, r = (seg >> 4) & 15, cs = (seg & 15) * 8;
        short* sp = &Sl[cpi*2176 + r*136 + cs];
        bf16x8 raw = *(bf16x8*)sp;
        const float mr = mrow[r], ilr = ilrow[r];
        float pv[8];
#pragma unroll
        for (int i = 0; i < 8; ++i) pv[i] = __expf(h2f_raw(raw[i]) - mr) * ilr;
        bf16x8 pb;
#pragma unroll
        for (int i = 0; i < 8; ++i) pb[i] = f2bf(pv[i]);
        *(bf16x8*)sp = pb;
        float4* ga = (float4*)(avg + ((size_t)(b*LO_) + r0 + r)*S_ + cpi*128 + cs);
        float4 v0 = {pv[0]*inv12, pv[1]*inv12, pv[2]*inv12, pv[3]*inv12};
        float4 v1 = {pv[4]*inv12, pv[5]*inv12, pv[6]*inv12, pv[7]*inv12};
        if (h != 0) {
          float4 o0 = ga[0], o1 = ga[1];
          v0.x += o0.x; v0.y += o0.y; v0.z += o0.z; v0.w += o0.w;
          v1.x += o1.x; v1.y += o1.y; v1.z += o1.z; v1.w += o1.w;
        }
        ga[0] = v0; ga[1] = v1;
      }
    }
    __syncthreads();

    // ---- Phase B: PV by MFMA ----
    f32x4 oacc = {};
#pragma unroll 1
    for (int cp8 = 0; cp8 < 8; ++cp8) {
      const __hip_bfloat16* vsrc = (cp8 < 4) ? v1 : v2;
      const int kb0 = (cp8 & 3) * 256;
      const uint4* gv = (const uint4*)(vsrc + ((size_t)(b*1024 + kb0 + srow))*E_ + h*64 + sc);
      uint4 vr[4];
#pragma unroll
      for (int i = 0; i < 4; ++i) vr[i] = gv[i];
      __syncthreads();
      const unsigned short* vs = (const unsigned short*)vr;
#pragma unroll
      for (int i = 0; i < 32; ++i) vTb[(sc + i)*264 + srow] = vs[i];
      __syncthreads();

      const int cpi = cp8*2 + cpr;
#pragma unroll
      for (int ksub = 0; ksub < 2; ++ksub) {
        const int kb = ksub * 64;
        bf16x8 pa0 = *(const bf16x8*)&Sl[cpi*2176 + l15*136 + kb +      quad*8];
        bf16x8 pa1 = *(const bf16x8*)&Sl[cpi*2176 + l15*136 + kb + 32 + quad*8];
        bf16x8 vb0 = *(const bf16x8*)&vTb[(ct*16 + l15)*264 + cpr*128 + kb +      quad*8];
        bf16x8 vb1 = *(const bf16x8*)&vTb[(ct*16 + l15)*264 + cpr*128 + kb + 32 + quad*8];
        oacc = MFMA16(pa0, vb0, oacc);
        oacc = MFMA16(pa1, vb1, oacc);
      }
    }

    // ---- merge cpr halves, plain ctx store (block owns these rows) ----
#pragma unroll
    for (int r = 0; r < 4; ++r) obuf[wv*256 + r*64 + lane] = oacc[r];
    __syncthreads();
#pragma unroll
    for (int e0 = 0; e0 < 2; ++e0) {
      const int e = tid + e0*512;
      const int row = e >> 6, dim = e & 63;
      const int idx = (row & 3)*64 + (row >> 2)*16 + (dim & 15);
      const float v = obuf[(dim >> 4)*256 + idx] + obuf[((dim >> 4) + 4)*256 + idx];
      ctx[((size_t)(b*LO_ + r0 + row))*E_ + h*64 + dim] = v;
    }
  }
}

// ================= launch =================
extern "C" void kernel_launch(void* const* d_in, const int* in_sizes, int n_in,
                              void* d_out, int out_size, void* d_ws, size_t ws_size,
                              hipStream_t stream) {
  const float* V    = (const float*)d_in[0];
  const float* Lm   = (const float*)d_in[1];
  const float* O    = (const float*)d_in[2];
  const float* mask = (const float*)d_in[3];
  const float* w1   = (const float*)d_in[4];
  const float* b1   = (const float*)d_in[5];
  const float* w2   = (const float*)d_in[6];
  const float* b2   = (const float*)d_in[7];
  const float* ow   = (const float*)d_in[8];
  const float* ob   = (const float*)d_in[9];
  float* out = (float*)d_out;

  // ws: bf16 q1,q2 (4096x768), k1,v1,k2,v2 (8192x768); fp32 ctx. ~75.5 MB
  __hip_bfloat16* ws  = (__hip_bfloat16*)d_ws;
  __hip_bfloat16* q1  = ws;
  __hip_bfloat16* q2  = q1 + (size_t)4096*768;
  __hip_bfloat16* k1  = q2 + (size_t)4096*768;
  __hip_bfloat16* v1  = k1 + (size_t)8192*768;
  __hip_bfloat16* k2  = v1 + (size_t)8192*768;
  __hip_bfloat16* v2  = k2 + (size_t)8192*768;
  float* ctx   = (float*)(v2 + (size_t)8192*768);

  dim3 blk(256);
  gemm_mfma<__hip_bfloat16><<<dim3(64, 12),  blk, 0, stream>>>(O,  w1,             b1,        q1, 4096);
  gemm_mfma<__hip_bfloat16><<<dim3(64, 12),  blk, 0, stream>>>(O,  w2,             b2,        q2, 4096);
  gemm_mfma<__hip_bfloat16><<<dim3(128, 12), blk, 0, stream>>>(V,  w1 + 768*768,   b1 + 768,  k1, 8192);
  gemm_mfma<__hip_bfloat16><<<dim3(128, 12), blk, 0, stream>>>(V,  w1 + 2*768*768, b1 + 1536, v1, 8192);
  gemm_mfma<__hip_bfloat16><<<dim3(128, 12), blk, 0, stream>>>(Lm, w2 + 768*768,   b2 + 768,  k2, 8192);
  gemm_mfma<__hip_bfloat16><<<dim3(128, 12), blk, 0, stream>>>(Lm, w2 + 2*768*768, b2 + 1536, v2, 8192);

  hipFuncSetAttribute((const void*)attn_main, hipFuncAttributeMaxDynamicSharedMemorySize, SMEM_MAIN);
  attn_main<<<dim3(256), dim3(512), SMEM_MAIN, stream>>>(q1, q2, k1, v1, k2, v2, mask,
                                                         ctx, out + (size_t)4096*768);

  gemm_mfma<float><<<dim3(64, 12), blk, 0, stream>>>(ctx, ow, ob, out, 4096);
}

// Round 6
// 1260.516 us; speedup vs baseline: 1.1541x; 1.1541x over previous
//
#include <hip/hip_runtime.h>
#include <hip/hip_bf16.h>
#include <hip/hip_fp16.h>
#include <type_traits>

#define B_  8
#define LO_ 512
#define E_  768
#define H_  12
#define S_  2048

typedef __attribute__((ext_vector_type(8))) short bf16x8;
typedef __attribute__((ext_vector_type(4))) float f32x4;
#define MFMA16(a,b,c) __builtin_amdgcn_mfma_f32_16x16x32_bf16(a, b, c, 0, 0, 0)

__device__ inline short f2bf(float f) {
  __hip_bfloat16 h = __float2bfloat16(f);
  return *reinterpret_cast<short*>(&h);
}
__device__ inline short f2h_raw(float f) {
  __half h = __float2half(f);
  return *reinterpret_cast<short*>(&h);
}
__device__ inline float h2f_raw(short s) {
  __half h = *reinterpret_cast<__half*>(&s);
  return __half2float(h);
}

// ================= MFMA GEMM: C[r][c] = sum_k A[r][k]*W[c][k] + bias[c] ==========
template <typename TC>
__global__ __launch_bounds__(256) void gemm_mfma(
    const float* __restrict__ A, const float* __restrict__ W,
    const float* __restrict__ bias, TC* __restrict__ C, int R)
{
  constexpr int N = 768, K = 768;
  __shared__ short As[64*72] __attribute__((aligned(16)));
  __shared__ short Ws[64*72] __attribute__((aligned(16)));
  const int tid = threadIdx.x, wv = tid >> 6, lane = tid & 63;
  const int quad = lane >> 4, l15 = lane & 15;
  const int r0 = blockIdx.x * 64, c0 = blockIdx.y * 64;
  const int srow = tid >> 2, sk = (tid & 3) * 16;

  f32x4 acc[4] = {};

  for (int k0 = 0; k0 < K; k0 += 64) {
    float a16[16], w16[16];
    const float4* ga = (const float4*)(A + (size_t)(r0 + srow) * K + k0 + sk);
    const float4* gw = (const float4*)(W + (size_t)(c0 + srow) * K + k0 + sk);
#pragma unroll
    for (int i = 0; i < 4; ++i) {
      float4 va = ga[i]; a16[4*i] = va.x; a16[4*i+1] = va.y; a16[4*i+2] = va.z; a16[4*i+3] = va.w;
      float4 vw = gw[i]; w16[4*i] = vw.x; w16[4*i+1] = vw.y; w16[4*i+2] = vw.z; w16[4*i+3] = vw.w;
    }
    bf16x8 pa[2], pw[2];
#pragma unroll
    for (int g = 0; g < 2; ++g)
#pragma unroll
      for (int i = 0; i < 8; ++i) { pa[g][i] = f2bf(a16[g*8+i]); pw[g][i] = f2bf(w16[g*8+i]); }
    __syncthreads();
    *(bf16x8*)&As[srow*72 + sk]     = pa[0];
    *(bf16x8*)&As[srow*72 + sk + 8] = pa[1];
    *(bf16x8*)&Ws[srow*72 + sk]     = pw[0];
    *(bf16x8*)&Ws[srow*72 + sk + 8] = pw[1];
    __syncthreads();

    bf16x8 af0 = *(const bf16x8*)&As[(wv*16 + l15)*72 +      quad*8];
    bf16x8 af1 = *(const bf16x8*)&As[(wv*16 + l15)*72 + 32 + quad*8];
#pragma unroll
    for (int ct = 0; ct < 4; ++ct) {
      bf16x8 bf0 = *(const bf16x8*)&Ws[(ct*16 + l15)*72 +      quad*8];
      bf16x8 bf1 = *(const bf16x8*)&Ws[(ct*16 + l15)*72 + 32 + quad*8];
      acc[ct] = MFMA16(af0, bf0, acc[ct]);
      acc[ct] = MFMA16(af1, bf1, acc[ct]);
    }
  }

#pragma unroll
  for (int ct = 0; ct < 4; ++ct) {
    const int col = c0 + ct*16 + l15;
    const float bv = bias[col];
#pragma unroll
    for (int r = 0; r < 4; ++r) {
      const int row = r0 + wv*16 + quad*4 + r;
      const float v = acc[ct][r] + bv;
      if constexpr (std::is_same_v<TC, float>) C[(size_t)row * N + col] = v;
      else                                     C[(size_t)row * N + col] = __float2bfloat16(v);
    }
  }
}

// ================= single-pass attention =================
// grid: (b, qt16) = 8*32 = 256 blocks, 512 thr = 8 waves, dynamic LDS 153,216 B.
// Per head: S=QK*scale+mask -> LDS fp16 (full 16x2048); exact softmax; in-place
// P transform (bf16) + pavg accumulated in REGISTERS (pacc[64]/thread, written
// once after the head loop -> no global RMW traffic); PV by MFMA; plain ctx store.
#define OFF_S   0          // [16 chunks][16][136] fp16 scores -> bf16 P   (69,632 B)
#define OFF_K   69632      // [256][72] bf16 K stage                        (36,864 B)
#define OFF_V   106496     // [64][264] bf16 V^T stage                      (33,792 B)
#define OFF_Q   140288     // [2][16][72] bf16 q1/q2 tiles                   (4,608 B)
#define OFF_O   144896     // [8][256] f32 obuf                              (8,192 B)
#define OFF_M   153088     // [16] f32 row max
#define OFF_IL  153152     // [16] f32 row 1/l
#define SMEM_MAIN 153216

__global__ __launch_bounds__(512, 1) void attn_main(
    const __hip_bfloat16* __restrict__ q1, const __hip_bfloat16* __restrict__ q2,
    const __hip_bfloat16* __restrict__ k1, const __hip_bfloat16* __restrict__ v1,
    const __hip_bfloat16* __restrict__ k2, const __hip_bfloat16* __restrict__ v2,
    const float* __restrict__ mask,
    float* __restrict__ ctx, float* __restrict__ avg)
{
  extern __shared__ char smem[];
  short* Sl   = (short*)(smem + OFF_S);    // chunk stride 2176 shorts, row stride 136
  short* kbuf = (short*)(smem + OFF_K);    // row stride 72
  unsigned short* vTb = (unsigned short*)(smem + OFF_V);  // row(dim) stride 264
  short* qtl  = (short*)(smem + OFF_Q);    // src stride 1152, row stride 72
  float* obuf = (float*)(smem + OFF_O);
  float* mrow = (float*)(smem + OFF_M);
  float* ilrow= (float*)(smem + OFF_IL);

  const int tid = threadIdx.x, wv = tid >> 6, lane = tid & 63;
  const int quad = lane >> 4, l15 = lane & 15;
  const int cpr = wv >> 2, ct = wv & 3;
  const int qt = blockIdx.x & 31, b = blockIdx.x >> 5;
  const int r0 = qt * 16;

  const int srow = tid >> 1, sc = (tid & 1) * 32;   // staging: 2 thr/row, 32 shorts each

  float pacc[64] = {};   // per-thread head-sum of P over its fixed 64 elements

#pragma unroll 1
  for (int h = 0; h < H_; ++h) {
    __syncthreads();  // previous head's LDS reads complete
    // ---- stage q1,q2 tiles ----
    if (tid < 128) {
      const int src = tid >> 6, row = (tid >> 2) & 15, c = (tid & 3) * 16;
      const uint4* g = (const uint4*)((src ? q2 : q1) + ((size_t)(b*LO_ + r0 + row))*E_ + h*64 + c);
      *(uint4*)&qtl[src*1152 + row*72 + c]     = g[0];
      *(uint4*)&qtl[src*1152 + row*72 + c + 8] = g[1];
    }
    __syncthreads();
    bf16x8 qa[2][2];
#pragma unroll
    for (int s = 0; s < 2; ++s)
#pragma unroll
      for (int ks = 0; ks < 2; ++ks)
        qa[s][ks] = *(const bf16x8*)&qtl[s*1152 + l15*72 + ks*32 + quad*8];

    // ---- Phase A: S = QK*scale + mask -> Sl (fp16) ----
#pragma unroll 1
    for (int cp8 = 0; cp8 < 8; ++cp8) {
      const __hip_bfloat16* ksrc = (cp8 < 4) ? k1 : k2;
      const int kb0 = (cp8 & 3) * 256;
      const uint4* gk = (const uint4*)(ksrc + ((size_t)(b*1024 + kb0 + srow))*E_ + h*64 + sc);
      uint4 kr[4];
#pragma unroll
      for (int i = 0; i < 4; ++i) kr[i] = gk[i];
      __syncthreads();
#pragma unroll
      for (int i = 0; i < 4; ++i) *(uint4*)&kbuf[srow*72 + sc + i*8] = kr[i];
      __syncthreads();

      const int s = cp8 >> 2;
#pragma unroll
      for (int ksub = 0; ksub < 2; ++ksub) {
        const int nb = wv*32 + ksub*16;
        bf16x8 b0 = *(const bf16x8*)&kbuf[(nb + l15)*72 +      quad*8];
        bf16x8 b1 = *(const bf16x8*)&kbuf[(nb + l15)*72 + 32 + quad*8];
        f32x4 sacc = {};
        sacc = MFMA16(qa[s][0], b0, sacc);
        sacc = MFMA16(qa[s][1], b1, sacc);
        const int gcol = cp8*256 + nb + l15;
        const int cpi = gcol >> 7, cic = gcol & 127;
#pragma unroll
        for (int r = 0; r < 4; ++r) {
          const int row = quad*4 + r;
          const float v = sacc[r]*0.125f + mask[(size_t)(r0 + row)*S_ + gcol];
          Sl[cpi*2176 + row*136 + cic] = f2h_raw(v);
        }
      }
    }
    __syncthreads();

    // ---- exact softmax stats per row (32 threads/row, same wave) ----
    {
      const int rr = tid >> 5, j = tid & 31;
      float m = -3.0e38f, l = 0.f;
#pragma unroll
      for (int p = 0; p < 8; ++p) {
        const int gcol = j*8 + p*256;
        const int cpi = gcol >> 7, cic = gcol & 127;
        bf16x8 raw = *(const bf16x8*)&Sl[cpi*2176 + rr*136 + cic];
#pragma unroll
        for (int i = 0; i < 8; ++i) {
          const float v = h2f_raw(raw[i]);
          const float mn = fmaxf(m, v);
          l = l*__expf(m - mn) + __expf(v - mn);
          m = mn;
        }
      }
#pragma unroll
      for (int off = 1; off < 32; off <<= 1) {
        const float mo = __shfl_xor(m, off, 64);
        const float lo = __shfl_xor(l, off, 64);
        const float mn = fmaxf(m, mo);
        l = l*__expf(m - mn) + lo*__expf(mo - mn);
        m = mn;
      }
      if (j == 0) { mrow[rr] = m; ilrow[rr] = 1.0f / l; }
    }
    __syncthreads();

    // ---- P transform in place (fp16 S -> bf16 P) + pacc accumulate ----
    // FULL unroll so pacc[] indices are compile-time (stay in VGPRs).
    {
#pragma unroll
      for (int it = 0; it < 8; ++it) {
        const int seg = tid + it*512;
        const int cpi = seg >> 8, r = (seg >> 4) & 15, cs = (seg & 15) * 8;
        short* sp = &Sl[cpi*2176 + r*136 + cs];
        bf16x8 raw = *(bf16x8*)sp;
        const float mr = mrow[r], ilr = ilrow[r];
        float pv[8];
#pragma unroll
        for (int i = 0; i < 8; ++i) pv[i] = __expf(h2f_raw(raw[i]) - mr) * ilr;
        bf16x8 pb;
#pragma unroll
        for (int i = 0; i < 8; ++i) pb[i] = f2bf(pv[i]);
        *(bf16x8*)sp = pb;
#pragma unroll
        for (int i = 0; i < 8; ++i) pacc[it*8 + i] += pv[i];
      }
    }
    // (no barrier needed here: Phase B's staging barrier orders Sl reads)

    // ---- Phase B: PV by MFMA ----
    f32x4 oacc = {};
#pragma unroll 1
    for (int cp8 = 0; cp8 < 8; ++cp8) {
      const __hip_bfloat16* vsrc = (cp8 < 4) ? v1 : v2;
      const int kb0 = (cp8 & 3) * 256;
      const uint4* gv = (const uint4*)(vsrc + ((size_t)(b*1024 + kb0 + srow))*E_ + h*64 + sc);
      uint4 vr[4];
#pragma unroll
      for (int i = 0; i < 4; ++i) vr[i] = gv[i];
      __syncthreads();   // previous reads of vTb done; also orders Sl P-writes
      const unsigned short* vs = (const unsigned short*)vr;
#pragma unroll
      for (int i = 0; i < 32; ++i) vTb[(sc + i)*264 + srow] = vs[i];
      __syncthreads();

      const int cpi = cp8*2 + cpr;
#pragma unroll
      for (int ksub = 0; ksub < 2; ++ksub) {
        const int kb = ksub * 64;
        bf16x8 pa0 = *(const bf16x8*)&Sl[cpi*2176 + l15*136 + kb +      quad*8];
        bf16x8 pa1 = *(const bf16x8*)&Sl[cpi*2176 + l15*136 + kb + 32 + quad*8];
        bf16x8 vb0 = *(const bf16x8*)&vTb[(ct*16 + l15)*264 + cpr*128 + kb +      quad*8];
        bf16x8 vb1 = *(const bf16x8*)&vTb[(ct*16 + l15)*264 + cpr*128 + kb + 32 + quad*8];
        oacc = MFMA16(pa0, vb0, oacc);
        oacc = MFMA16(pa1, vb1, oacc);
      }
    }

    // ---- merge cpr halves, plain ctx store (block owns these rows) ----
#pragma unroll
    for (int r = 0; r < 4; ++r) obuf[wv*256 + r*64 + lane] = oacc[r];
    __syncthreads();
#pragma unroll
    for (int e0 = 0; e0 < 2; ++e0) {
      const int e = tid + e0*512;
      const int row = e >> 6, dim = e & 63;
      const int idx = (row & 3)*64 + (row >> 2)*16 + (dim & 15);
      const float v = obuf[(dim >> 4)*256 + idx] + obuf[((dim >> 4) + 4)*256 + idx];
      ctx[((size_t)(b*LO_ + r0 + row))*E_ + h*64 + dim] = v;
    }
  }

  // ---- write head-averaged attention once (fp32) ----
  {
    constexpr float inv12 = 1.0f / 12.0f;
#pragma unroll
    for (int it = 0; it < 8; ++it) {
      const int seg = tid + it*512;
      const int cpi = seg >> 8, r = (seg >> 4) & 15, cs = (seg & 15) * 8;
      float4* ga = (float4*)(avg + ((size_t)(b*LO_) + r0 + r)*S_ + cpi*128 + cs);
      float4 v0 = {pacc[it*8+0]*inv12, pacc[it*8+1]*inv12, pacc[it*8+2]*inv12, pacc[it*8+3]*inv12};
      float4 v1 = {pacc[it*8+4]*inv12, pacc[it*8+5]*inv12, pacc[it*8+6]*inv12, pacc[it*8+7]*inv12};
      ga[0] = v0; ga[1] = v1;
    }
  }
}

// ================= launch =================
extern "C" void kernel_launch(void* const* d_in, const int* in_sizes, int n_in,
                              void* d_out, int out_size, void* d_ws, size_t ws_size,
                              hipStream_t stream) {
  const float* V    = (const float*)d_in[0];
  const float* Lm   = (const float*)d_in[1];
  const float* O    = (const float*)d_in[2];
  const float* mask = (const float*)d_in[3];
  const float* w1   = (const float*)d_in[4];
  const float* b1   = (const float*)d_in[5];
  const float* w2   = (const float*)d_in[6];
  const float* b2   = (const float*)d_in[7];
  const float* ow   = (const float*)d_in[8];
  const float* ob   = (const float*)d_in[9];
  float* out = (float*)d_out;

  // ws: bf16 q1,q2 (4096x768), k1,v1,k2,v2 (8192x768); fp32 ctx. ~75.5 MB
  __hip_bfloat16* ws  = (__hip_bfloat16*)d_ws;
  __hip_bfloat16* q1  = ws;
  __hip_bfloat16* q2  = q1 + (size_t)4096*768;
  __hip_bfloat16* k1  = q2 + (size_t)4096*768;
  __hip_bfloat16* v1  = k1 + (size_t)8192*768;
  __hip_bfloat16* k2  = v1 + (size_t)8192*768;
  __hip_bfloat16* v2  = k2 + (size_t)8192*768;
  float* ctx   = (float*)(v2 + (size_t)8192*768);

  dim3 blk(256);
  gemm_mfma<__hip_bfloat16><<<dim3(64, 12),  blk, 0, stream>>>(O,  w1,             b1,        q1, 4096);
  gemm_mfma<__hip_bfloat16><<<dim3(64, 12),  blk, 0, stream>>>(O,  w2,             b2,        q2, 4096);
  gemm_mfma<__hip_bfloat16><<<dim3(128, 12), blk, 0, stream>>>(V,  w1 + 768*768,   b1 + 768,  k1, 8192);
  gemm_mfma<__hip_bfloat16><<<dim3(128, 12), blk, 0, stream>>>(V,  w1 + 2*768*768, b1 + 1536, v1, 8192);
  gemm_mfma<__hip_bfloat16><<<dim3(128, 12), blk, 0, stream>>>(Lm, w2 + 768*768,   b2 + 768,  k2, 8192);
  gemm_mfma<__hip_bfloat16><<<dim3(128, 12), blk, 0, stream>>>(Lm, w2 + 2*768*768, b2 + 1536, v2, 8192);

  hipFuncSetAttribute((const void*)attn_main, hipFuncAttributeMaxDynamicSharedMemorySize, SMEM_MAIN);
  attn_main<<<dim3(256), dim3(512), SMEM_MAIN, stream>>>(q1, q2, k1, v1, k2, v2, mask,
                                                         ctx, out + (size_t)4096*768);

  gemm_mfma<float><<<dim3(64, 12), blk, 0, stream>>>(ctx, ow, ob, out, 4096);
}